// Round 3
// baseline (496.213 us; speedup 1.0000x reference)
//
#include <hip/hip_runtime.h>
#include <hip/hip_bf16.h>
#include <stdint.h>

typedef __attribute__((ext_vector_type(8))) short short8;
typedef __attribute__((ext_vector_type(4))) float f32x4;
typedef __attribute__((ext_vector_type(8))) unsigned short ushort8v;

__device__ __forceinline__ unsigned short f2bf(float f) {
  union { float f; uint32_t u; } v; v.f = f;
  uint32_t u = v.u;
  u += 0x7fffu + ((u >> 16) & 1u);   // round-to-nearest-even
  return (unsigned short)(u >> 16);
}
__device__ __forceinline__ unsigned short f2h(float f) {
  union { _Float16 h; unsigned short u; } v; v.h = (_Float16)f; return v.u;
}
__device__ __forceinline__ float h2f(unsigned short u) {
  union { _Float16 h; unsigned short u; } v; v.u = u; return (float)v.h;
}

typedef const __attribute__((address_space(1))) unsigned int* gas_ptr;
typedef __attribute__((address_space(3))) unsigned int* las_ptr;

// DMA 16B per lane: LDS dst = wave-uniform base + lane*16 (hardware rule)
__device__ __forceinline__ void async16(const unsigned short* g, unsigned short* l) {
  __builtin_amdgcn_global_load_lds((gas_ptr)g, (las_ptr)l, 16, 0, 0);
}

#define FENCE() asm volatile("" ::: "memory")
#define BARRIER() do { FENCE(); __builtin_amdgcn_s_barrier(); FENCE(); } while (0)

// ---------------------------------------------------------------------------
// 256x256 pipelined 4-phase GEMM:  C = A * B^T, all-bf16.  A:[M,K], B:[N,K].
// 512 threads = 8 waves (2M x 4N); per-wave C = 128x64 as acc[8][4] of
// 16x16x32 bf16 MFMA fragments.
// LDS = 2 buffers x {A,B} x 2 K-half regions; region = 256 rows x 32 cols
// bf16 (16 KB), total 128 KB.  16B chunk s of row r at slot s ^ ((r>>1)&3)
// (source pre-swizzled, LDS dest linear) -> frag ds_read_b128 2-way (free).
//
// LDS-read schedule is BALANCED at 6 reads/wave/phase (was 8/4/0/12): the
// LDS pipe (~2800 cyc/tile demand) is the binding resource and must overlap
// the MFMA clusters (~620 cyc CU-wide backlog per phase) instead of bursting.
// Per K-tile: 4 phases, 4 barriers, ONE counted vmcnt(4):
//   ph1: MFMA(a0,b0,n0-1); read a1[0..5];            stage B-h1(t+1); bar
//   ph2: MFMA(a0,b0,n2-3); read a1[6..7],b1[0..3];   stage A-h0(t+2); bar
//   ph3: MFMA(a1,b1,n0-1); read a0'[0..5] (t+1);     stage B-h0(t+2); bar
//   ph4: stage A-h1(t+2); vmcnt(4); bar; read a0'[6..7],b0'[0..3]; MFMA(a1,b1,n2-3)
// vmcnt(4) audit (per-wave queue at ph4, oldest first, 2 instrs/stage):
//   leftover {B-h0(t+1), A-h1(t+1)} + {B-h1(t+1), A-h0(t+2), B-h0(t+2),
//   A-h1(t+2)} = 12; drain 8 -> B-h0(t+1), A-h1(t+1), B-h1(t+1), A-h0(t+2)
//   landed.  Covers: a1(t+1)@ph1, b1(t+1)@ph2, a0'(t+2)@ph3 [one tile spare],
//   b0'(t+1)@this-ph4-post-wait.  Barrier after wait makes it block-wide.
// Overwrite hazards: each region's consuming MFMA (lgkm-forced) is >=1
// barrier before the overwriting DMA issue (audited per region).
// EPI 0: bf16 = val + bias[col]; EPI 1: fp16 = val*scale; EPI 2: f32 = val*scale
// ---------------------------------------------------------------------------
#define BM 256
#define BN 256
#define BK 64
#define RGN 8192   // ushorts per region (256 rows x 32 cols)

template<int EPI>
__global__ __launch_bounds__(512, 2) void gemm256(
    const unsigned short* __restrict__ Abase,
    const unsigned short* __restrict__ Bbase,
    void* __restrict__ Cbase, const float* __restrict__ bias, float scale,
    int lda, int ldb, int ldc, int K, int mtiles, int ntiles,
    long long sA, long long sB, long long sC)
{
  __shared__ __align__(16) unsigned short lds[8 * RGN];   // 128 KB

  const int tid  = threadIdx.x;
  const int nwg  = (int)gridDim.x;
  const int flat = (int)blockIdx.x;
  // XCD-aware bijective swizzle (all launches have nwg % 8 == 0)
  const int swz = (flat & 7) * (nwg >> 3) + (flat >> 3);
  const int per = mtiles * ntiles;
  const int z   = swz / per;
  const int rm  = swz - z * per;
  const int mb  = rm / ntiles;
  const int nb  = rm - mb * ntiles;
  const int m0  = mb * BM;
  const int n0  = nb * BN;

  const int wave = tid >> 6;
  const int lane = tid & 63;
  const int l16  = lane & 15;
  const int quad = lane >> 4;
  const int wm   = wave >> 2;   // 0..1 -> row offset wm*128
  const int wn   = wave & 3;    // 0..3 -> col offset wn*64

  const unsigned short* A = Abase + (size_t)z * (size_t)sA;
  const unsigned short* B = Bbase + (size_t)z * (size_t)sB;

  // per-thread fragment read offsets (ushort units within a region)
  const int RA   = wm * 128 + l16;                    // + mt*16 -> row
  const int RB   = wn * 64  + l16;                    // + nt*16 -> row
  const int offA = RA * 32 + (quad ^ ((RA >> 1) & 3)) * 8;   // + mt*512
  const int offB = RB * 32 + (quad ^ ((RB >> 1) & 3)) * 8;   // + nt*512

  f32x4 acc[8][4] = {};

  const int nt = K / BK;

  // region index: buf*4 + ab*2 + h   (ab: 0=A, 1=B; h: K-half)
  auto stageA = [&](int kt, int h, int b) {
    unsigned short* rgn = lds + (size_t)(b * 4 + h) * RGN;
    #pragma unroll
    for (int i = 0; i < 2; ++i) {
      const int c  = i * 512 + tid;            // chunk index [0,1024)
      const int r  = c >> 2;                   // row
      const int s  = c & 3;                    // LDS slot in row
      const int sc = s ^ ((r >> 1) & 3);       // global chunk (pre-swizzle)
      async16(A + (size_t)(m0 + r) * lda + kt * 64 + h * 32 + sc * 8,
              rgn + (size_t)(i * 512 + wave * 64) * 8);
    }
  };
  auto stageB = [&](int kt, int h, int b) {
    unsigned short* rgn = lds + (size_t)(b * 4 + 2 + h) * RGN;
    #pragma unroll
    for (int i = 0; i < 2; ++i) {
      const int c  = i * 512 + tid;
      const int r  = c >> 2;
      const int s  = c & 3;
      const int sc = s ^ ((r >> 1) & 3);
      async16(B + (size_t)(n0 + r) * ldb + kt * 64 + h * 32 + sc * 8,
              rgn + (size_t)(i * 512 + wave * 64) * 8);
    }
  };

  // prologue: tile0 complete + tile1 {A-h0, B-h0, A-h1} (3 half-regions ahead)
  // vmcnt(4): drain 10 of 14 -> tile0 (8) + A-h0(1) (needed by t=0 ph3 reads)
  stageA(0, 0, 0); stageB(0, 0, 0); stageA(0, 1, 0); stageB(0, 1, 0);
  stageA(1, 0, 1); stageB(1, 0, 1); stageA(1, 1, 1);
  asm volatile("s_waitcnt vmcnt(4)" ::: "memory");
  BARRIER();

#define MFMA_QUAD(AF, BF, J0)                                                   \
  do {                                                                          \
    __builtin_amdgcn_s_setprio(1);                                              \
    _Pragma("unroll")                                                           \
    for (int mt = 0; mt < 8; ++mt) {                                            \
      acc[mt][J0]     = __builtin_amdgcn_mfma_f32_16x16x32_bf16(                \
          AF[mt], BF[J0],     acc[mt][J0],     0, 0, 0);                        \
      acc[mt][J0 + 1] = __builtin_amdgcn_mfma_f32_16x16x32_bf16(                \
          AF[mt], BF[J0 + 1], acc[mt][J0 + 1], 0, 0, 0);                        \
    }                                                                           \
    __builtin_amdgcn_s_setprio(0);                                              \
  } while (0)

  short8 a0[8], a1[8], b0[4], b1[4];
  // pre-read tile-0 h0 fragments (one-time lgkm exposure)
  {
    const unsigned short* Ah0 = lds;
    const unsigned short* Bh0 = lds + (size_t)2 * RGN;
    #pragma unroll
    for (int mt = 0; mt < 8; ++mt) a0[mt] = *(const short8*)&Ah0[offA + mt * 512];
    #pragma unroll
    for (int j = 0; j < 4; ++j)    b0[j]  = *(const short8*)&Bh0[offB + j * 512];
  }

  int cur = 0;
  for (int t = 0; t < nt; ++t, cur ^= 1) {
    const unsigned short* Ah1  = lds + (size_t)(cur * 4 + 1) * RGN;
    const unsigned short* Bh1  = lds + (size_t)(cur * 4 + 3) * RGN;
    const unsigned short* nAh0 = lds + (size_t)((cur ^ 1) * 4 + 0) * RGN;
    const unsigned short* nBh0 = lds + (size_t)((cur ^ 1) * 4 + 2) * RGN;

    // ---- phase 1: MFMA h0 x n0-1; read a1[0..5]; stage B-h1(t+1)
    MFMA_QUAD(a0, b0, 0);
    #pragma unroll
    for (int mt = 0; mt < 6; ++mt) a1[mt] = *(const short8*)&Ah1[offA + mt * 512];
    if (t + 1 < nt) stageB(t + 1, 1, cur ^ 1);
    BARRIER();

    // ---- phase 2: MFMA h0 x n2-3; read a1[6..7] + b1[0..3]; stage A-h0(t+2)
    MFMA_QUAD(a0, b0, 2);
    a1[6] = *(const short8*)&Ah1[offA + 6 * 512];
    a1[7] = *(const short8*)&Ah1[offA + 7 * 512];
    #pragma unroll
    for (int j = 0; j < 4; ++j) b1[j] = *(const short8*)&Bh1[offB + j * 512];
    if (t + 2 < nt) stageA(t + 2, 0, cur);
    BARRIER();

    // ---- phase 3: MFMA h1 x n0-1; read a0'[0..5] (tile t+1); stage B-h0(t+2)
    MFMA_QUAD(a1, b1, 0);
    if (t + 1 < nt) {
      #pragma unroll
      for (int mt = 0; mt < 6; ++mt) a0[mt] = *(const short8*)&nAh0[offA + mt * 512];
    }
    if (t + 2 < nt) stageB(t + 2, 0, cur);
    BARRIER();

    // ---- phase 4: stage A-h1(t+2); counted vmcnt; barrier;
    //      read a0'[6..7] + b0'[0..3]; MFMA h1 x n2-3
    if (t + 2 < nt) stageA(t + 2, 1, cur);
    if (t < nt - 2)       asm volatile("s_waitcnt vmcnt(4)" ::: "memory");
    else if (t == nt - 2) asm volatile("s_waitcnt vmcnt(0)" ::: "memory");
    BARRIER();
    if (t + 1 < nt) {
      a0[6] = *(const short8*)&nAh0[offA + 6 * 512];
      a0[7] = *(const short8*)&nAh0[offA + 7 * 512];
      #pragma unroll
      for (int j = 0; j < 4; ++j) b0[j] = *(const short8*)&nBh0[offB + j * 512];
    }
    MFMA_QUAD(a1, b1, 2);
  }

  // ---- epilogue.  D layout: col = lane&15, row = quad*4 + reg ----
  #pragma unroll
  for (int mt = 0; mt < 8; ++mt) {
    const int Rg = m0 + wm * 128 + mt * 16 + quad * 4;
    #pragma unroll
    for (int j = 0; j < 4; ++j) {
      const int Cg = n0 + wn * 64 + j * 16 + l16;
      float badd = 0.f;
      if (EPI == 0) badd = bias[Cg];
      #pragma unroll
      for (int r = 0; r < 4; ++r) {
        const size_t off = (size_t)z * (size_t)sC + (size_t)(Rg + r) * ldc + Cg;
        const float val = acc[mt][j][r];
        if (EPI == 0) {
          ((unsigned short*)Cbase)[off] = f2bf(val + badd);
        } else if (EPI == 1) {
          ((unsigned short*)Cbase)[off] = f2h(val * scale);
        } else {
          ((float*)Cbase)[off] = val * scale;
        }
      }
    }
  }
}

// ---------------------------------------------------------------------------
// fp32 -> bf16 elementwise for the three [8,2048,1024] inputs (z selects).
// ---------------------------------------------------------------------------
__global__ __launch_bounds__(256) void cvt3_bf16(
    const float* __restrict__ a, const float* __restrict__ b,
    const float* __restrict__ c,
    unsigned short* __restrict__ oa, unsigned short* __restrict__ ob,
    unsigned short* __restrict__ oc)
{
  const float* src = blockIdx.z == 0 ? a : (blockIdx.z == 1 ? b : c);
  unsigned short* dst = blockIdx.z == 0 ? oa : (blockIdx.z == 1 ? ob : oc);
  const size_t base = ((size_t)blockIdx.x * 256 + threadIdx.x) * 8;
  const float4 t0 = *(const float4*)(src + base);
  const float4 t1 = *(const float4*)(src + base + 4);
  ushort8v h;
  h[0] = f2bf(t0.x); h[1] = f2bf(t0.y); h[2] = f2bf(t0.z); h[3] = f2bf(t0.w);
  h[4] = f2bf(t1.x); h[5] = f2bf(t1.y); h[6] = f2bf(t1.z); h[7] = f2bf(t1.w);
  *(ushort8v*)(dst + base) = h;
}

// ---------------------------------------------------------------------------
// Wq [1024x1024] fp32 -> Wt [1024x1024] bf16 transposed
// ---------------------------------------------------------------------------
__global__ __launch_bounds__(256) void transpose_w(
    const float* __restrict__ W, unsigned short* __restrict__ Wt)
{
  __shared__ float tile[64][65];
  const int k0 = blockIdx.x * 64;
  const int n0 = blockIdx.y * 64;
  #pragma unroll
  for (int i = 0; i < 16; ++i) {
    int lin = threadIdx.x + i * 256;
    int r = lin >> 6, c = lin & 63;
    tile[r][c] = W[(size_t)(k0 + r) * 1024 + n0 + c];
  }
  __syncthreads();
  #pragma unroll
  for (int i = 0; i < 16; ++i) {
    int lin = threadIdx.x + i * 256;
    int r = lin >> 6, c = lin & 63;
    Wt[(size_t)(n0 + r) * 1024 + k0 + c] = f2bf(tile[c][r]);
  }
}

// ---------------------------------------------------------------------------
// v [b][2048][1024] bf16 -> vT [b][1024][2048] bf16
// ---------------------------------------------------------------------------
__global__ __launch_bounds__(256) void transpose_v(
    const unsigned short* __restrict__ V, unsigned short* __restrict__ VT)
{
  __shared__ unsigned short tile[64][66];
  const int b  = blockIdx.z;
  const int s0 = blockIdx.x * 64;
  const int d0 = blockIdx.y * 64;
  const unsigned short* Vb  = V  + (size_t)b * 2048 * 1024;
  unsigned short*       VTb = VT + (size_t)b * 1024 * 2048;
  #pragma unroll
  for (int i = 0; i < 16; ++i) {
    int lin = threadIdx.x + i * 256;
    int r = lin >> 6, c = lin & 63;
    tile[r][c] = Vb[(size_t)(s0 + r) * 1024 + d0 + c];
  }
  __syncthreads();
  #pragma unroll
  for (int i = 0; i < 16; ++i) {
    int lin = threadIdx.x + i * 256;
    int r = lin >> 6, c = lin & 63;
    VTb[(size_t)(d0 + r) * 2048 + s0 + c] = tile[c][r];
  }
}

// ---------------------------------------------------------------------------
// Row softmax: read fp16 logits row (2048), write bf16 P row (2048).
// ---------------------------------------------------------------------------
__global__ __launch_bounds__(256) void softmax_rows(
    const unsigned short* __restrict__ Lh, unsigned short* __restrict__ P)
{
  const int row  = blockIdx.x;
  const unsigned short* pin = Lh + (size_t)row * 2048;
  unsigned short*       pout = P + (size_t)row * 2048;
  const int tid  = threadIdx.x;
  const int lane = tid & 63;
  const int wave = tid >> 6;

  const ushort8v h = ((const ushort8v*)pin)[tid];
  float x[8];
  #pragma unroll
  for (int e = 0; e < 8; ++e) x[e] = h2f(h[e]);

  float mx = x[0];
  #pragma unroll
  for (int e = 1; e < 8; ++e) mx = fmaxf(mx, x[e]);
  #pragma unroll
  for (int o = 32; o > 0; o >>= 1) mx = fmaxf(mx, __shfl_xor(mx, o));
  __shared__ float redm[4];
  if (lane == 0) redm[wave] = mx;
  __syncthreads();
  mx = fmaxf(fmaxf(redm[0], redm[1]), fmaxf(redm[2], redm[3]));

  float s = 0.f;
  #pragma unroll
  for (int e = 0; e < 8; ++e) { x[e] = __expf(x[e] - mx); s += x[e]; }
  #pragma unroll
  for (int o = 32; o > 0; o >>= 1) s += __shfl_xor(s, o);
  __shared__ float reds[4];
  if (lane == 0) reds[wave] = s;
  __syncthreads();
  s = reds[0] + reds[1] + reds[2] + reds[3];

  const float inv = 1.0f / s;
  ushort8v o8;
  #pragma unroll
  for (int e = 0; e < 8; ++e) o8[e] = f2bf(x[e] * inv);
  ((ushort8v*)pout)[tid] = o8;
}

// ---------------------------------------------------------------------------
extern "C" void kernel_launch(void* const* d_in, const int* in_sizes, int n_in,
                              void* d_out, int out_size, void* d_ws, size_t ws_size,
                              hipStream_t stream)
{
  const float* query = (const float*)d_in[0];
  const float* key   = (const float*)d_in[1];
  const float* value = (const float*)d_in[2];
  const float* Wq    = (const float*)d_in[3];
  const float* bq    = (const float*)d_in[4];
  float* out = (float*)d_out;

  // workspace (MB offsets), peak 226 MB:
  //   Wt  [0,2)     bf16 W^T
  //   Xq  [2,34) Xk [34,66) Xv [66,98)    bf16 inputs (contiguous -> one GEMM)
  //   q   [98,130) k [130,162) v [162,194) bf16 projections (contiguous)
  //   vT  [2,34)    over dead Xq
  //   lgH [34,98)   fp16 logits over dead Xk/Xv
  //   P   [98,162)  bf16 probs over dead q/k
  char* ws = (char*)d_ws;
  unsigned short* Wt  = (unsigned short*)(ws);
  unsigned short* Xq  = (unsigned short*)(ws + ((size_t)2   << 20));
  unsigned short* Xk  = (unsigned short*)(ws + ((size_t)34  << 20));
  unsigned short* Xv  = (unsigned short*)(ws + ((size_t)66  << 20));
  unsigned short* q   = (unsigned short*)(ws + ((size_t)98  << 20));
  unsigned short* v   = (unsigned short*)(ws + ((size_t)162 << 20));
  unsigned short* vT  = (unsigned short*)(ws + ((size_t)2   << 20));
  unsigned short* lgH = (unsigned short*)(ws + ((size_t)34  << 20));
  unsigned short* P   = (unsigned short*)(ws + ((size_t)98  << 20));

  // 1. W transpose->bf16 ; inputs fp32->bf16
  transpose_w<<<dim3(16, 16, 1), 256, 0, stream>>>(Wq, Wt);
  cvt3_bf16<<<dim3(8192, 1, 3), 256, 0, stream>>>(query, key, value, Xq, Xk, Xv);

  // 2. projections (single dispatch over contiguous X/q-k-v):
  //    bf16 = X @ Wt^T + bq   (M=16384, N=1024, K=1024, z=3) -> 64x4x3 = 768 wg
  gemm256<0><<<dim3(768, 1, 1), 512, 0, stream>>>(
      Xq, Wt, q, bq, 1.0f, 1024, 1024, 1024, 1024, 64, 4,
      (long long)16384 * 1024, 0, (long long)16384 * 1024);

  // 3. v -> vT  (writes over dead Xq)
  transpose_v<<<dim3(32, 16, 8), 256, 0, stream>>>(v, vT);

  // 4. logits[fp16] = (q @ k^T)/32  per batch (M=N=2048, K=1024) -> 8x8x8 = 512 wg
  gemm256<1><<<dim3(512, 1, 1), 512, 0, stream>>>(
      q, q + (size_t)32 * 1024 * 1024 / 2, lgH, nullptr, 0.03125f,
      1024, 1024, 2048, 1024, 8, 8,
      (long long)2048 * 1024, (long long)2048 * 1024, (long long)2048 * 2048);

  // 5. softmax rows -> bf16 P (writes over dead q/k)
  softmax_rows<<<dim3(8 * 2048, 1, 1), 256, 0, stream>>>(lgH, P);

  // 6. out[f32] = P @ vT^T  per batch (M=2048, N=1024, K=2048) -> 8x4x8 = 256 wg
  gemm256<2><<<dim3(256, 1, 1), 512, 0, stream>>>(
      P, vT, out, nullptr, 1.0f, 2048, 2048, 1024, 2048, 8, 4,
      (long long)2048 * 2048, (long long)1024 * 2048, (long long)2048 * 1024);
}

// Round 4
// 490.189 us; speedup vs baseline: 1.0123x; 1.0123x over previous
//
#include <hip/hip_runtime.h>
#include <hip/hip_bf16.h>
#include <stdint.h>

typedef __attribute__((ext_vector_type(8))) short short8;
typedef __attribute__((ext_vector_type(4))) float f32x4;
typedef __attribute__((ext_vector_type(8))) unsigned short ushort8v;

__device__ __forceinline__ unsigned short f2bf(float f) {
  union { float f; uint32_t u; } v; v.f = f;
  uint32_t u = v.u;
  u += 0x7fffu + ((u >> 16) & 1u);   // round-to-nearest-even
  return (unsigned short)(u >> 16);
}
__device__ __forceinline__ unsigned short f2h(float f) {
  union { _Float16 h; unsigned short u; } v; v.h = (_Float16)f; return v.u;
}
__device__ __forceinline__ float h2f(unsigned short u) {
  union { _Float16 h; unsigned short u; } v; v.u = u; return (float)v.h;
}

typedef const __attribute__((address_space(1))) unsigned int* gas_ptr;
typedef __attribute__((address_space(3))) unsigned int* las_ptr;

// DMA 16B per lane: LDS dst = wave-uniform base + lane*16 (hardware rule)
__device__ __forceinline__ void async16(const unsigned short* g, unsigned short* l) {
  __builtin_amdgcn_global_load_lds((gas_ptr)g, (las_ptr)l, 16, 0, 0);
}

#define FENCE() asm volatile("" ::: "memory")
#define BARRIER() do { FENCE(); __builtin_amdgcn_s_barrier(); FENCE(); } while (0)

// ---------------------------------------------------------------------------
// Faithful m201-style 8-phase 256x256 GEMM:  C = A * B^T, all-bf16.
// A:[M,K], B:[N,K].  512 threads = 8 waves (2M x 4N); per-wave C = 128x64
// as acc[8][4] of 16x16x32 bf16 MFMA fragments.
//
// LDS: 8 regions x 16KB = 128KB.  Region = M-half (A: rows hm*128+(0..127))
// or N-half (B) x full BK=64 cols.  Region idx = buf*4 + {0:A0,1:A1,2:B0,3:B1}.
// Swizzle: 16B chunk s of local row r holds global chunk s ^ ((r>>1)&7)
// (source pre-swizzled, LDS dest linear).  Fragment-read key reduces to
// (l16>>1)&7 for ALL frags (row deltas are multiples of 16) -> 2-way banks.
//
// Iteration I = 2 K-tiles (t0=2I on buf0, t1 on buf1), 8 phases.  Phase:
//   [ds_read frags for THIS phase] [stage <=1 region] BARRIER;
//   lgkmcnt(0); sched_barrier(0); setprio(1); 16 MFMA; setprio(0); BARRIER;
// Phase p computes C-quadrant: ph1-4 on buf0: Q(0,0),(0,1),(1,0),(1,1);
// ph5-8 same on buf1.  Reads: ph1/5: A(qr0)8+B(qc0)4; ph2/6: B(qc1)4;
// ph3/7: A(qr1)8; ph4/8: none.
// Stages: ph1: buf1.A1(t1); ph3: buf0.B0,B1(t0+2); ph4: buf0.A0(t0+2);
// ph5: buf0.A1(t0+2); ph7: buf1.B0,B1(t1+2); ph8: buf1.A0(t1+2).
// vmcnt(6) ONLY at ph4/ph8 (1 stage = 2 DMA instrs):
//  - ph4: outstanding {ph4.A0,ph3.B1,ph3.B0,ph1.A1, prev:ph8.A0,ph7.B1,ph7.B0}
//    = 7 stages; keep 3 -> retires exactly buf1(t1).  Last iter: vmcnt(0).
//  - ph8: outstanding {ph8.A0,ph7.B1,ph7.B0,ph5.A1,ph4.A0,ph3.B1,ph3.B0}
//    = 7 stages; keep 3 -> retires exactly buf0(t0+2).
// Deadness: every region's overwriting stage issues >=1 barrier after the
// lgkmcnt(0) that completed its last reads (audited per region).
// EPI 0: bf16 = val + bias[col]; EPI 1: fp16 = val*scale; EPI 2: f32 = val*scale
// ---------------------------------------------------------------------------
#define BM 256
#define BN 256
#define BK 64
#define RGN 8192   // ushorts per region (128 rows x 64 cols)

template<int EPI>
__global__ __launch_bounds__(512, 2) void gemm256(
    const unsigned short* __restrict__ Abase,
    const unsigned short* __restrict__ Bbase,
    void* __restrict__ Cbase, const float* __restrict__ bias, float scale,
    int lda, int ldb, int ldc, int K, int mtiles, int ntiles,
    long long sA, long long sB, long long sC)
{
  __shared__ __align__(16) unsigned short lds[8 * RGN];   // 128 KB

  const int tid  = threadIdx.x;
  const int nwg  = (int)gridDim.x;
  const int flat = (int)blockIdx.x;
  // XCD-aware bijective swizzle (all launches have nwg % 8 == 0)
  const int swz = (flat & 7) * (nwg >> 3) + (flat >> 3);
  const int per = mtiles * ntiles;
  const int z   = swz / per;
  const int rm  = swz - z * per;
  const int mb  = rm / ntiles;
  const int nb  = rm - mb * ntiles;
  const int m0  = mb * BM;
  const int n0  = nb * BN;

  const int wave = tid >> 6;
  const int lane = tid & 63;
  const int l16  = lane & 15;
  const int quad = lane >> 4;
  const int wm   = wave >> 2;   // 0..1 -> row offset wm*128
  const int wn   = wave & 3;    // 0..3 -> col offset wn*64

  const unsigned short* A = Abase + (size_t)z * (size_t)sA;
  const unsigned short* B = Bbase + (size_t)z * (size_t)sB;

  // per-thread fragment read bases (ushort units within a region)
  const int Kx  = (l16 >> 1) & 7;
  const int sh0 = (quad ^ Kx) * 8;          // k-half 0 slot offset
  const int sh1 = ((quad + 4) ^ Kx) * 8;    // k-half 1
  const int aOff = l16 * 64;
  const int bOff = (wn & 1) * 4096 + l16 * 64;

  f32x4 acc[8][4] = {};
  const int nt = K / BK;

  // stage one 16KB region (2 DMA instrs/wave): rows rowBase+(0..127),
  // cols kt*64 + swizzled 16B chunks
  auto stage = [&](const unsigned short* S, int ldx, int rowBase, int kt, int rgn) {
    unsigned short* dst = lds + (size_t)rgn * RGN;
    #pragma unroll
    for (int i = 0; i < 2; ++i) {
      const int c  = i * 512 + tid;          // chunk idx [0,1024)
      const int r  = c >> 3;                 // local row 0..127
      const int s  = c & 7;                  // LDS slot
      const int gc = s ^ ((r >> 1) & 7);     // global chunk (pre-swizzle)
      async16(S + (size_t)(rowBase + r) * ldx + kt * 64 + gc * 8,
              dst + (size_t)c * 8);          // linear: base + lane*16  ✓
    }
  };

  short8 a[4][2], b0[2][2], b1[2][2];

  auto readA = [&](const unsigned short* Ar, int qr) {
    #pragma unroll
    for (int mt = 0; mt < 4; ++mt) {
      const int base = qr * 4096 + mt * 1024 + aOff;
      a[mt][0] = *(const short8*)&Ar[base + sh0];
      a[mt][1] = *(const short8*)&Ar[base + sh1];
    }
  };
  auto readB = [&](const unsigned short* Br, int qc, short8 (&b)[2][2]) {
    #pragma unroll
    for (int ntl = 0; ntl < 2; ++ntl) {
      const int base = bOff + qc * 2048 + ntl * 1024;
      b[ntl][0] = *(const short8*)&Br[base + sh0];
      b[ntl][1] = *(const short8*)&Br[base + sh1];
    }
  };
  auto mfmaQ = [&](int qr, int qc, short8 (&b)[2][2]) {
    __builtin_amdgcn_s_setprio(1);
    #pragma unroll
    for (int h = 0; h < 2; ++h)
      #pragma unroll
      for (int mt = 0; mt < 4; ++mt)
        #pragma unroll
        for (int ntl = 0; ntl < 2; ++ntl)
          acc[qr * 4 + mt][qc * 2 + ntl] =
              __builtin_amdgcn_mfma_f32_16x16x32_bf16(
                  a[mt][h], b[ntl][h], acc[qr * 4 + mt][qc * 2 + ntl], 0, 0, 0);
    __builtin_amdgcn_s_setprio(0);
  };

#define PHASE_SYNC() do { BARRIER();                                  \
    asm volatile("s_waitcnt lgkmcnt(0)" ::: "memory");                \
    __builtin_amdgcn_sched_barrier(0); } while (0)

  // prologue: buf0(0)={B0,B1,A0,A1}, buf1(1)={B0,B1,A0}; vmcnt(6) retires
  // the 4 oldest = buf0(0); barrier publishes.
  stage(B, ldb, n0,       0, 2); stage(B, ldb, n0 + 128, 0, 3);
  stage(A, lda, m0,       0, 0); stage(A, lda, m0 + 128, 0, 1);
  stage(B, ldb, n0,       1, 6); stage(B, ldb, n0 + 128, 1, 7);
  stage(A, lda, m0,       1, 4);
  asm volatile("s_waitcnt vmcnt(6)" ::: "memory");
  BARRIER();

  const unsigned short* A0r = lds + (size_t)(0 + wm) * RGN;
  const unsigned short* B0r = lds + (size_t)(2 + (wn >> 1)) * RGN;
  const unsigned short* A1r = lds + (size_t)(4 + wm) * RGN;
  const unsigned short* B1r = lds + (size_t)(6 + (wn >> 1)) * RGN;

  const int nit = nt >> 1;
  for (int I = 0; I < nit; ++I) {
    const int t0 = 2 * I, t1 = 2 * I + 1;
    const bool st0 = (t0 + 2 < nt), st1 = (t1 + 2 < nt), last = (I == nit - 1);

    // ---- ph1: Q(0,0) on buf0
    readA(A0r, 0); readB(B0r, 0, b0);
    stage(A, lda, m0 + 128, t1, 5);                 // buf1.A1 <- t1
    PHASE_SYNC(); mfmaQ(0, 0, b0); BARRIER();
    // ---- ph2: Q(0,1)
    readB(B0r, 1, b1);
    PHASE_SYNC(); mfmaQ(0, 1, b1); BARRIER();
    // ---- ph3: Q(1,0)
    readA(A0r, 1);
    if (st0) { stage(B, ldb, n0, t0 + 2, 2); stage(B, ldb, n0 + 128, t0 + 2, 3); }
    PHASE_SYNC(); mfmaQ(1, 0, b0); BARRIER();
    // ---- ph4: Q(1,1); counted vmcnt -> buf1(t1) landed
    if (st0) stage(A, lda, m0, t0 + 2, 0);
    if (!last) asm volatile("s_waitcnt vmcnt(6)" ::: "memory");
    else       asm volatile("s_waitcnt vmcnt(0)" ::: "memory");
    PHASE_SYNC(); mfmaQ(1, 1, b1); BARRIER();

    // ---- ph5: Q(0,0) on buf1
    readA(A1r, 0); readB(B1r, 0, b0);
    if (st0) stage(A, lda, m0 + 128, t0 + 2, 1);
    PHASE_SYNC(); mfmaQ(0, 0, b0); BARRIER();
    // ---- ph6: Q(0,1)
    readB(B1r, 1, b1);
    PHASE_SYNC(); mfmaQ(0, 1, b1); BARRIER();
    // ---- ph7: Q(1,0)
    readA(A1r, 1);
    if (st1) { stage(B, ldb, n0, t1 + 2, 6); stage(B, ldb, n0 + 128, t1 + 2, 7); }
    PHASE_SYNC(); mfmaQ(1, 0, b0); BARRIER();
    // ---- ph8: Q(1,1); counted vmcnt -> buf0(t0+2) landed
    if (st1) stage(A, lda, m0, t1 + 2, 4);
    if (!last) asm volatile("s_waitcnt vmcnt(6)" ::: "memory");
    PHASE_SYNC(); mfmaQ(1, 1, b1); BARRIER();
  }

  // ---- epilogue.  D layout: col = lane&15, row = quad*4 + reg ----
  #pragma unroll
  for (int mt = 0; mt < 8; ++mt) {
    const int Rg = m0 + wm * 128 + mt * 16 + quad * 4;
    #pragma unroll
    for (int j = 0; j < 4; ++j) {
      const int Cg = n0 + wn * 64 + j * 16 + l16;
      float badd = 0.f;
      if (EPI == 0) badd = bias[Cg];
      #pragma unroll
      for (int r = 0; r < 4; ++r) {
        const size_t off = (size_t)z * (size_t)sC + (size_t)(Rg + r) * ldc + Cg;
        const float val = acc[mt][j][r];
        if (EPI == 0) {
          ((unsigned short*)Cbase)[off] = f2bf(val + badd);
        } else if (EPI == 1) {
          ((unsigned short*)Cbase)[off] = f2h(val * scale);
        } else {
          ((float*)Cbase)[off] = val * scale;
        }
      }
    }
  }
}

// ---------------------------------------------------------------------------
// fp32 -> bf16 elementwise for the three [8,2048,1024] inputs (z selects).
// ---------------------------------------------------------------------------
__global__ __launch_bounds__(256) void cvt3_bf16(
    const float* __restrict__ a, const float* __restrict__ b,
    const float* __restrict__ c,
    unsigned short* __restrict__ oa, unsigned short* __restrict__ ob,
    unsigned short* __restrict__ oc)
{
  const float* src = blockIdx.z == 0 ? a : (blockIdx.z == 1 ? b : c);
  unsigned short* dst = blockIdx.z == 0 ? oa : (blockIdx.z == 1 ? ob : oc);
  const size_t base = ((size_t)blockIdx.x * 256 + threadIdx.x) * 8;
  const float4 t0 = *(const float4*)(src + base);
  const float4 t1 = *(const float4*)(src + base + 4);
  ushort8v h;
  h[0] = f2bf(t0.x); h[1] = f2bf(t0.y); h[2] = f2bf(t0.z); h[3] = f2bf(t0.w);
  h[4] = f2bf(t1.x); h[5] = f2bf(t1.y); h[6] = f2bf(t1.z); h[7] = f2bf(t1.w);
  *(ushort8v*)(dst + base) = h;
}

// ---------------------------------------------------------------------------
// Wq [1024x1024] fp32 -> Wt [1024x1024] bf16 transposed
// ---------------------------------------------------------------------------
__global__ __launch_bounds__(256) void transpose_w(
    const float* __restrict__ W, unsigned short* __restrict__ Wt)
{
  __shared__ float tile[64][65];
  const int k0 = blockIdx.x * 64;
  const int n0 = blockIdx.y * 64;
  #pragma unroll
  for (int i = 0; i < 16; ++i) {
    int lin = threadIdx.x + i * 256;
    int r = lin >> 6, c = lin & 63;
    tile[r][c] = W[(size_t)(k0 + r) * 1024 + n0 + c];
  }
  __syncthreads();
  #pragma unroll
  for (int i = 0; i < 16; ++i) {
    int lin = threadIdx.x + i * 256;
    int r = lin >> 6, c = lin & 63;
    Wt[(size_t)(n0 + r) * 1024 + k0 + c] = f2bf(tile[c][r]);
  }
}

// ---------------------------------------------------------------------------
// v [b][2048][1024] bf16 -> vT [b][1024][2048] bf16
// ---------------------------------------------------------------------------
__global__ __launch_bounds__(256) void transpose_v(
    const unsigned short* __restrict__ V, unsigned short* __restrict__ VT)
{
  __shared__ unsigned short tile[64][66];
  const int b  = blockIdx.z;
  const int s0 = blockIdx.x * 64;
  const int d0 = blockIdx.y * 64;
  const unsigned short* Vb  = V  + (size_t)b * 2048 * 1024;
  unsigned short*       VTb = VT + (size_t)b * 1024 * 2048;
  #pragma unroll
  for (int i = 0; i < 16; ++i) {
    int lin = threadIdx.x + i * 256;
    int r = lin >> 6, c = lin & 63;
    tile[r][c] = Vb[(size_t)(s0 + r) * 1024 + d0 + c];
  }
  __syncthreads();
  #pragma unroll
  for (int i = 0; i < 16; ++i) {
    int lin = threadIdx.x + i * 256;
    int r = lin >> 6, c = lin & 63;
    VTb[(size_t)(d0 + r) * 2048 + s0 + c] = tile[c][r];
  }
}

// ---------------------------------------------------------------------------
// Row softmax: read fp16 logits row (2048), write bf16 P row (2048).
// ---------------------------------------------------------------------------
__global__ __launch_bounds__(256) void softmax_rows(
    const unsigned short* __restrict__ Lh, unsigned short* __restrict__ P)
{
  const int row  = blockIdx.x;
  const unsigned short* pin = Lh + (size_t)row * 2048;
  unsigned short*       pout = P + (size_t)row * 2048;
  const int tid  = threadIdx.x;
  const int lane = tid & 63;
  const int wave = tid >> 6;

  const ushort8v h = ((const ushort8v*)pin)[tid];
  float x[8];
  #pragma unroll
  for (int e = 0; e < 8; ++e) x[e] = h2f(h[e]);

  float mx = x[0];
  #pragma unroll
  for (int e = 1; e < 8; ++e) mx = fmaxf(mx, x[e]);
  #pragma unroll
  for (int o = 32; o > 0; o >>= 1) mx = fmaxf(mx, __shfl_xor(mx, o));
  __shared__ float redm[4];
  if (lane == 0) redm[wave] = mx;
  __syncthreads();
  mx = fmaxf(fmaxf(redm[0], redm[1]), fmaxf(redm[2], redm[3]));

  float s = 0.f;
  #pragma unroll
  for (int e = 0; e < 8; ++e) { x[e] = __expf(x[e] - mx); s += x[e]; }
  #pragma unroll
  for (int o = 32; o > 0; o >>= 1) s += __shfl_xor(s, o);
  __shared__ float reds[4];
  if (lane == 0) reds[wave] = s;
  __syncthreads();
  s = reds[0] + reds[1] + reds[2] + reds[3];

  const float inv = 1.0f / s;
  ushort8v o8;
  #pragma unroll
  for (int e = 0; e < 8; ++e) o8[e] = f2bf(x[e] * inv);
  ((ushort8v*)pout)[tid] = o8;
}

// ---------------------------------------------------------------------------
extern "C" void kernel_launch(void* const* d_in, const int* in_sizes, int n_in,
                              void* d_out, int out_size, void* d_ws, size_t ws_size,
                              hipStream_t stream)
{
  const float* query = (const float*)d_in[0];
  const float* key   = (const float*)d_in[1];
  const float* value = (const float*)d_in[2];
  const float* Wq    = (const float*)d_in[3];
  const float* bq    = (const float*)d_in[4];
  float* out = (float*)d_out;

  // workspace (MB offsets), peak 226 MB:
  //   Wt  [0,2)     bf16 W^T
  //   Xq  [2,34) Xk [34,66) Xv [66,98)    bf16 inputs (contiguous -> one GEMM)
  //   q   [98,130) k [130,162) v [162,194) bf16 projections (contiguous)
  //   vT  [2,34)    over dead Xq
  //   lgH [34,98)   fp16 logits over dead Xk/Xv
  //   P   [98,162)  bf16 probs over dead q/k
  char* ws = (char*)d_ws;
  unsigned short* Wt  = (unsigned short*)(ws);
  unsigned short* Xq  = (unsigned short*)(ws + ((size_t)2   << 20));
  unsigned short* Xk  = (unsigned short*)(ws + ((size_t)34  << 20));
  unsigned short* Xv  = (unsigned short*)(ws + ((size_t)66  << 20));
  unsigned short* q   = (unsigned short*)(ws + ((size_t)98  << 20));
  unsigned short* v   = (unsigned short*)(ws + ((size_t)162 << 20));
  unsigned short* vT  = (unsigned short*)(ws + ((size_t)2   << 20));
  unsigned short* lgH = (unsigned short*)(ws + ((size_t)34  << 20));
  unsigned short* P   = (unsigned short*)(ws + ((size_t)98  << 20));

  // 1. W transpose->bf16 ; inputs fp32->bf16
  transpose_w<<<dim3(16, 16, 1), 256, 0, stream>>>(Wq, Wt);
  cvt3_bf16<<<dim3(8192, 1, 3), 256, 0, stream>>>(query, key, value, Xq, Xk, Xv);

  // 2. projections (single dispatch over contiguous X/q-k-v):
  //    bf16 = X @ Wt^T + bq   (M=16384, N=1024, K=1024, z=3) -> 64x4x3 = 768 wg
  gemm256<0><<<dim3(768, 1, 1), 512, 0, stream>>>(
      Xq, Wt, q, bq, 1.0f, 1024, 1024, 1024, 1024, 64, 4,
      (long long)16384 * 1024, 0, (long long)16384 * 1024);

  // 3. v -> vT  (writes over dead Xq)
  transpose_v<<<dim3(32, 16, 8), 256, 0, stream>>>(v, vT);

  // 4. logits[fp16] = (q @ k^T)/32  per batch (M=N=2048, K=1024) -> 8x8x8 = 512 wg
  gemm256<1><<<dim3(512, 1, 1), 512, 0, stream>>>(
      q, q + (size_t)32 * 1024 * 1024 / 2, lgH, nullptr, 0.03125f,
      1024, 1024, 2048, 1024, 8, 8,
      (long long)2048 * 1024, (long long)2048 * 1024, (long long)2048 * 2048);

  // 5. softmax rows -> bf16 P (writes over dead q/k)
  softmax_rows<<<dim3(8 * 2048, 1, 1), 256, 0, stream>>>(lgH, P);

  // 6. out[f32] = P @ vT^T  per batch (M=2048, N=1024, K=2048) -> 8x4x8 = 256 wg
  gemm256<2><<<dim3(256, 1, 1), 512, 0, stream>>>(
      P, vT, out, nullptr, 1.0f, 2048, 2048, 1024, 2048, 8, 4,
      (long long)2048 * 2048, (long long)1024 * 2048, (long long)2048 * 1024);
}